// Round 1
// baseline (1159.713 us; speedup 1.0000x reference)
//
#include <hip/hip_runtime.h>

// Problem constants (fixed shapes from reference)
#define NSEQ 64
#define NHEAD 32
#define KVH 8
#define G 4            // query heads per kv head
#define D 128          // head size
#define BS 16          // kv cache block size (tokens)
#define MAX_BPS 128    // max blocks per seq
#define CHUNK 256      // tokens per flash-decoding chunk
#define MAX_CHUNKS 8   // 2048 / 256
#define NP (NSEQ * KVH * MAX_CHUNKS * G)   // number of partials = 16384

// Kernel 1: one WG per (seq, kv_head, chunk); 4 waves = 4 query heads of the
// GQA group streaming the same K/V blocks (L1/L2 serve the 4x reuse).
// Per 16-token block: lane (t = lane&15, p = lane>>4) computes a 32-dim
// partial of score[t], reduced via shfl_xor(16|32). Online softmax per wave.
// PV: lane owns output dims (2*lane, 2*lane+1).
__global__ __launch_bounds__(256) void pa_partial_kernel(
    const float* __restrict__ q,          // [NSEQ, NHEAD, D]
    const float* __restrict__ kcache,     // [NB, KVH, BS, D]
    const float* __restrict__ vcache,     // [NB, KVH, BS, D]
    const float* __restrict__ scale_ptr,  // scalar
    const int*   __restrict__ block_tables, // [NSEQ, MAX_BPS]
    const int*   __restrict__ seq_lens,   // [NSEQ]
    const float* __restrict__ slopes,     // [NHEAD]
    float* __restrict__ pm,               // [NP]
    float* __restrict__ pl,               // [NP]
    float* __restrict__ pacc)             // [NP, D]
{
    const int bx = blockIdx.x;
    const int c  = bx & 7;
    const int kv = (bx >> 3) & 7;
    const int s  = bx >> 6;

    const int len    = seq_lens[s];
    const int cstart = c * CHUNK;
    if (cstart >= len) return;

    const int g    = threadIdx.x >> 6;
    const int lane = threadIdx.x & 63;
    const int t    = lane & 15;   // token within kv block
    const int p    = lane >> 4;   // dim quarter for score partial
    const int h    = kv * G + g;  // query head

    const float scale = scale_ptr[0];
    const float slope = slopes[h];

    // q fragment: dims [p*32, p*32+32), pre-scaled
    float4 qr[8];
    {
        const float4* qp = (const float4*)(q + ((size_t)s * NHEAD + h) * D + p * 32);
        #pragma unroll
        for (int i = 0; i < 8; i++) {
            float4 v = qp[i];
            v.x *= scale; v.y *= scale; v.z *= scale; v.w *= scale;
            qr[i] = v;
        }
    }

    const int ctok = min(CHUNK, len - cstart);
    const int nb   = (ctok + BS - 1) / BS;

    float m = -1e30f;
    float l = 0.0f;
    float accx = 0.0f, accy = 0.0f;
    const int d0 = 2 * lane;

    const int* bt = block_tables + (size_t)s * MAX_BPS + (cstart / BS);

    for (int b = 0; b < nb; b++) {
        const int blk = bt[b];
        const float* kb = kcache + ((size_t)blk * KVH + kv) * (BS * D);
        const float* vb = vcache + ((size_t)blk * KVH + kv) * (BS * D);

        // ---- scores ----
        float sc = 0.0f;
        {
            const float4* kp = (const float4*)(kb + t * D + p * 32);
            #pragma unroll
            for (int i = 0; i < 8; i++) {
                float4 k4 = kp[i];
                sc += qr[i].x * k4.x + qr[i].y * k4.y + qr[i].z * k4.z + qr[i].w * k4.w;
            }
        }
        sc += __shfl_xor(sc, 16);
        sc += __shfl_xor(sc, 32);   // all lanes with same t now hold full dot

        const int pos = cstart + b * BS + t;
        sc += slope * (float)(pos - (len - 1));    // ALiBi
        if (pos >= len) sc = -1e30f;               // mask tail

        // block max over the 16 tokens (tokens replicated 4x across 16-lane groups)
        float mb = sc;
        mb = fmaxf(mb, __shfl_xor(mb, 1));
        mb = fmaxf(mb, __shfl_xor(mb, 2));
        mb = fmaxf(mb, __shfl_xor(mb, 4));
        mb = fmaxf(mb, __shfl_xor(mb, 8));

        const float mn    = fmaxf(m, mb);
        const float alpha = __expf(m - mn);        // m=-1e30 first iter -> 0, no NaN
        const float pt    = __expf(sc - mn);       // masked -> exp(~-1e30) = 0

        float ps = pt;
        ps += __shfl_xor(ps, 1);
        ps += __shfl_xor(ps, 2);
        ps += __shfl_xor(ps, 4);
        ps += __shfl_xor(ps, 8);                   // sum over 16 tokens

        l = l * alpha + ps;
        accx *= alpha;
        accy *= alpha;
        m = mn;

        // ---- PV: acc[d0..d0+1] += sum_t p[t] * v[t][d] ----
        #pragma unroll
        for (int tt = 0; tt < 16; tt++) {
            const float pv = __shfl(pt, tt);       // lane tt holds token tt
            const float2 v2 = *(const float2*)(vb + tt * D + d0);
            accx += pv * v2.x;
            accy += pv * v2.y;
        }
    }

    const size_t P = (size_t)bx * G + g;
    *(float2*)(pacc + P * D + d0) = make_float2(accx, accy);
    if (lane == 0) { pm[P] = m; pl[P] = l; }
}

// Kernel 2: combine chunk partials. One WG per (seq, head), 128 threads = dims.
__global__ __launch_bounds__(128) void pa_reduce_kernel(
    const float* __restrict__ pm,
    const float* __restrict__ pl,
    const float* __restrict__ pacc,
    const int*   __restrict__ seq_lens,
    float* __restrict__ out)              // [NSEQ, NHEAD, D]
{
    const int sh = blockIdx.x;
    const int s  = sh >> 5;
    const int h  = sh & 31;
    const int kv = h >> 2;
    const int g  = h & 3;

    const int len = seq_lens[s];
    const int nc  = (len + CHUNK - 1) / CHUNK;
    const int d   = threadIdx.x;

    float M = -1e30f;
    for (int c = 0; c < nc; c++) {
        const size_t P = ((size_t)((s * 8 + kv) * 8 + c)) * G + g;
        M = fmaxf(M, pm[P]);
    }
    float num = 0.0f, den = 0.0f;
    for (int c = 0; c < nc; c++) {
        const size_t P = ((size_t)((s * 8 + kv) * 8 + c)) * G + g;
        const float w = __expf(pm[P] - M);
        den += w * pl[P];
        num += w * pacc[P * D + d];
    }
    out[((size_t)s * NHEAD + h) * D + d] = num / den;
}

extern "C" void kernel_launch(void* const* d_in, const int* in_sizes, int n_in,
                              void* d_out, int out_size, void* d_ws, size_t ws_size,
                              hipStream_t stream) {
    const float* q            = (const float*)d_in[0];
    const float* kcache       = (const float*)d_in[1];
    const float* vcache       = (const float*)d_in[2];
    // d_in[3] = num_kv_heads (compile-time constant KVH)
    const float* scale_ptr    = (const float*)d_in[4];
    const int*   block_tables = (const int*)d_in[5];
    const int*   seq_lens     = (const int*)d_in[6];
    // d_in[7] = block_size (BS), d_in[8] = max_seq_len (2048)
    const float* slopes       = (const float*)d_in[9];
    float* out = (float*)d_out;

    float* ws   = (float*)d_ws;
    float* pm   = ws;                 // NP floats
    float* pl   = ws + NP;            // NP floats
    float* pacc = ws + 2 * (size_t)NP; // NP*D floats

    const int grid1 = NSEQ * KVH * MAX_CHUNKS;   // 4096
    pa_partial_kernel<<<grid1, 256, 0, stream>>>(
        q, kcache, vcache, scale_ptr, block_tables, seq_lens, slopes, pm, pl, pacc);

    const int grid2 = NSEQ * NHEAD;              // 2048
    pa_reduce_kernel<<<grid2, 128, 0, stream>>>(pm, pl, pacc, seq_lens, out);
}